// Round 14
// baseline (1667.488 us; speedup 1.0000x reference)
//
#include <hip/hip_runtime.h>
#include <math.h>

#define V_SZ   65
#define C_DIM  512
#define T_SEQ  256
#define H_N    8
#define HS_D   64
#define L_N    8
#define N_TOK  16384   // B*T = 64*256
#define LN_EPS 1e-5f
#define SM_SCALE 0.044194173824159216f  // 512^-0.5 (scaled by n_embd, per reference)

typedef unsigned short ushortT;
typedef __attribute__((ext_vector_type(8))) short    short8;
typedef __attribute__((ext_vector_type(8))) ushortT  ushort8;
typedef __attribute__((ext_vector_type(4))) float    f32x4;

typedef __attribute__((address_space(3))) unsigned int        lds_uint;
typedef const __attribute__((address_space(1))) unsigned int  glob_uint;

__device__ inline ushortT f2bf(float f) {
    unsigned int u = __float_as_uint(f);
    u = (u + 0x7fffu + ((u >> 16) & 1u)) >> 16;   // RNE
    return (ushortT)u;
}
__device__ inline float bf2f(ushortT u) {
    return __uint_as_float(((unsigned int)u) << 16);
}

// ---------------------------------------------------------------------------
// Embedding -> bf16 residual stream (sum computed fp32, rounded once)
// ---------------------------------------------------------------------------
__global__ void embed_kernel(const int* __restrict__ idx,
                             const float* __restrict__ tok,
                             const float* __restrict__ pos,
                             ushortT* __restrict__ x) {
    int i = blockIdx.x * blockDim.x + threadIdx.x;   // 8-elem chunk index
    const int NC8 = N_TOK * C_DIM / 8;
    if (i >= NC8) return;
    int c8 = i % (C_DIM / 8);
    int n  = i / (C_DIM / 8);
    int t  = n % T_SEQ;
    int tk = idx[n];
    const float4* ta = (const float4*)&tok[(size_t)tk * C_DIM + c8 * 8];
    const float4* pa = (const float4*)&pos[(size_t)t  * C_DIM + c8 * 8];
    float4 a0 = ta[0], a1 = ta[1], p0 = pa[0], p1 = pa[1];
    ushort8 r;
    r[0] = f2bf(a0.x + p0.x); r[1] = f2bf(a0.y + p0.y);
    r[2] = f2bf(a0.z + p0.z); r[3] = f2bf(a0.w + p0.w);
    r[4] = f2bf(a1.x + p1.x); r[5] = f2bf(a1.y + p1.y);
    r[6] = f2bf(a1.z + p1.z); r[7] = f2bf(a1.w + p1.w);
    *(ushort8*)&x[(size_t)i * 8] = r;
}

// ---------------------------------------------------------------------------
// Weight transpose+cast: src[K][N] f32 -> dst[N][K] bf16, batched over L.
// ---------------------------------------------------------------------------
__global__ __launch_bounds__(256) void tcast_kernel(const float* __restrict__ src,
                                                    ushortT* __restrict__ dst,
                                                    int K, int N) {
    __shared__ float tile[32][33];
    size_t lo = (size_t)blockIdx.z * K * N;
    int n0 = blockIdx.x * 32, k0 = blockIdx.y * 32;
    int tx = threadIdx.x & 31, ty = threadIdx.x >> 5;
    #pragma unroll
    for (int s = 0; s < 4; s++) {
        int kk = ty + s * 8;
        tile[kk][tx] = src[lo + (size_t)(k0 + kk) * N + n0 + tx];
    }
    __syncthreads();
    #pragma unroll
    for (int s = 0; s < 4; s++) {
        int nn = ty + s * 8;
        dst[lo + (size_t)(n0 + nn) * K + k0 + tx] = f2bf(tile[tx][nn]);
    }
}

// lm head weight: lm_w[512][65] f32 -> lmT[128][512] bf16 (rows >=65 zero)
__global__ __launch_bounds__(256) void lmcast_kernel(const float* __restrict__ w,
                                                     ushortT* __restrict__ dst) {
    int n = blockIdx.x;            // 0..127
    for (int k = threadIdx.x; k < C_DIM; k += 256)
        dst[(size_t)n * C_DIM + k] = (n < V_SZ) ? f2bf(w[(size_t)k * V_SZ + n]) : (ushortT)0;
}

// ---------------------------------------------------------------------------
// LayerNorm: one wave per row of C=512, bf16 in/out, fp32 stats.
// ---------------------------------------------------------------------------
__global__ __launch_bounds__(256) void ln_kernel(const ushortT* __restrict__ in,
                                                 const float* __restrict__ g,
                                                 const float* __restrict__ b,
                                                 ushortT* __restrict__ outv) {
    int wave = threadIdx.x >> 6;
    int lane = threadIdx.x & 63;
    int row  = blockIdx.x * 4 + wave;
    ushort8 raw = *(const ushort8*)&in[(size_t)row * C_DIM + lane * 8];
    float v[8];
    #pragma unroll
    for (int k = 0; k < 8; k++) v[k] = bf2f(raw[k]);
    float s = 0.f;
    #pragma unroll
    for (int k = 0; k < 8; k++) s += v[k];
    #pragma unroll
    for (int m = 32; m >= 1; m >>= 1) s += __shfl_xor(s, m, 64);
    float mean = s * (1.0f / C_DIM);
    float vs = 0.f;
    #pragma unroll
    for (int k = 0; k < 8; k++) { float d = v[k] - mean; vs += d * d; }
    #pragma unroll
    for (int m = 32; m >= 1; m >>= 1) vs += __shfl_xor(vs, m, 64);
    float rstd = rsqrtf(vs * (1.0f / C_DIM) + LN_EPS);
    float gv[8], bv[8];
    *(float4*)&gv[0] = *(const float4*)&g[lane * 8];
    *(float4*)&gv[4] = *(const float4*)&g[lane * 8 + 4];
    *(float4*)&bv[0] = *(const float4*)&b[lane * 8];
    *(float4*)&bv[4] = *(const float4*)&b[lane * 8 + 4];
    ushort8 pack;
    #pragma unroll
    for (int k = 0; k < 8; k++) pack[k] = f2bf((v[k] - mean) * rstd * gv[k] + bv[k]);
    *(ushort8*)&outv[(size_t)row * C_DIM + lane * 8] = pack;
}

// ---------------------------------------------------------------------------
// ROUND-4 PROVEN bf16 MFMA GEMM core (BK=32). qkv / lm head.
// EPI: 1 bf16 | 2 +bias,relu -> bf16 | 4 lm head f32
// ---------------------------------------------------------------------------
template<int EPI>
__device__ __forceinline__ void gemm_core(const ushortT* __restrict__ A,
                                          const ushortT* __restrict__ Bt,
                                          const float* __restrict__ bias,
                                          void* __restrict__ outp,
                                          int N, int K,
                                          int mBase, int nBase) {
    __shared__ __align__(16) ushortT As[128 * 32];
    __shared__ __align__(16) ushortT Bs[128 * 32];
    const int tid = threadIdx.x;
    const int w = tid >> 6, lane = tid & 63;
    const int wr = w >> 1, wc = w & 1;
    const int l15 = lane & 15, lg = lane >> 4;
    const int srow = (lane >> 2);
    const int sslot = lane & 3;

    f32x4 acc[4][4];
    #pragma unroll
    for (int i = 0; i < 4; i++)
        #pragma unroll
        for (int j = 0; j < 4; j++)
            acc[i][j] = {0.f, 0.f, 0.f, 0.f};

    for (int k0 = 0; k0 < K; k0 += 32) {
        #pragma unroll
        for (int t = 0; t < 2; t++) {
            int r = w * 32 + t * 16 + srow;
            int ks = sslot ^ ((r >> 1) & 3);
            const ushortT* ga = &A[(size_t)(mBase + r) * K + k0 + ks * 8];
            __builtin_amdgcn_global_load_lds((glob_uint*)ga,
                (lds_uint*)&As[(w * 32 + t * 16) * 32], 16, 0, 0);
            const ushortT* gb = &Bt[(size_t)(nBase + r) * K + k0 + ks * 8];
            __builtin_amdgcn_global_load_lds((glob_uint*)gb,
                (lds_uint*)&Bs[(w * 32 + t * 16) * 32], 16, 0, 0);
        }
        __syncthreads();
        short8 af[4], bfr[4];
        #pragma unroll
        for (int i = 0; i < 4; i++) {
            int r = wr * 64 + i * 16 + l15;
            int cb = (lg * 16) ^ (((r >> 1) & 3) << 4);
            af[i] = *(const short8*)((const char*)As + r * 64 + cb);
        }
        #pragma unroll
        for (int j = 0; j < 4; j++) {
            int r = wc * 64 + j * 16 + l15;
            int cb = (lg * 16) ^ (((r >> 1) & 3) << 4);
            bfr[j] = *(const short8*)((const char*)Bs + r * 64 + cb);
        }
        #pragma unroll
        for (int i = 0; i < 4; i++)
            #pragma unroll
            for (int j = 0; j < 4; j++)
                acc[i][j] = __builtin_amdgcn_mfma_f32_16x16x32_bf16(af[i], bfr[j], acc[i][j], 0, 0, 0);
        __syncthreads();
    }

    int lr = lg * 4;
    #pragma unroll
    for (int i = 0; i < 4; i++) {
        #pragma unroll
        for (int j = 0; j < 4; j++) {
            int col = nBase + wc * 64 + j * 16 + l15;
            if (EPI == 4 && col >= V_SZ) continue;
            #pragma unroll
            for (int q = 0; q < 4; q++) {
                size_t row = (size_t)(mBase + wr * 64 + i * 16 + lr + q);
                float vv = acc[i][j][q];
                if (EPI >= 2) vv += bias[col];
                if (EPI == 2) vv = fmaxf(vv, 0.f);
                if (EPI == 1)      ((ushortT*)outp)[row * N + col] = f2bf(vv);
                else if (EPI == 2) ((ushortT*)outp)[row * N + col] = f2bf(vv);
                else               ((float*)outp)[row * V_SZ + col] = vv;   // EPI 4
            }
        }
    }
}

template<int EPI>
__global__ __launch_bounds__(256, 2) void gemm_bf16(const ushortT* __restrict__ A,
                                                    const ushortT* __restrict__ Bt,
                                                    const float* __restrict__ bias,
                                                    void* __restrict__ outp,
                                                    int N, int K) {
    gemm_core<EPI>(A, Bt, bias, outp, N, K, blockIdx.x * 128, blockIdx.y * 128);
}

__global__ __launch_bounds__(256, 2) void gemm_qkv(const ushortT* __restrict__ A,
                                                   const ushortT* __restrict__ bq,
                                                   const ushortT* __restrict__ bk,
                                                   const ushortT* __restrict__ bv,
                                                   ushortT* __restrict__ oq,
                                                   ushortT* __restrict__ ok,
                                                   ushortT* __restrict__ ov,
                                                   int N, int K) {
    const ushortT* Bt = (blockIdx.z == 0) ? bq : (blockIdx.z == 1) ? bk : bv;
    ushortT*       o  = (blockIdx.z == 0) ? oq : (blockIdx.z == 1) ? ok : ov;
    gemm_core<1>(A, Bt, nullptr, o, N, K, blockIdx.x * 128, blockIdx.y * 128);
}

// ---------------------------------------------------------------------------
// NEW: barrier-free GEMM for w1 — per-wave PRIVATE double-buffered LDS.
// Wave (wr,wc) stages its own A rows [wr*64, +64) and B rows [wc*64, +64)
// into its private region (4 waves x 2 buf x 8 KB = 64 KB), waits on its OWN
// vmcnt (per-wave counter), reads only what it wrote -> NO s_barrier at all.
// WAR hazards resolved by program order (compiler lgkm-waits reads before the
// MFMAs that precede the next stage). A/B each staged 2x (2nd copy L2-hits).
// Swizzle unchanged (local row key, both sides). K-order per output element
// unchanged -> bit-identical numerics. EPI=2: +bias, relu -> bf16.
// ---------------------------------------------------------------------------
__global__ __launch_bounds__(256, 2) void gemm_nobar(const ushortT* __restrict__ A,
                                                     const ushortT* __restrict__ Bt,
                                                     const float* __restrict__ bias,
                                                     ushortT* __restrict__ outp,
                                                     int N, int K) {
    __shared__ __align__(16) ushortT Abuf[4][2][64 * 32];   // 32 KB
    __shared__ __align__(16) ushortT Bbuf[4][2][64 * 32];   // 32 KB
    const int tid = threadIdx.x;
    const int w = tid >> 6, lane = tid & 63;
    const int wr = w >> 1, wc = w & 1;
    const int l15 = lane & 15, lg = lane >> 4;
    const int aRow0 = blockIdx.x * 128 + wr * 64;   // this wave's A rows
    const int bRow0 = blockIdx.y * 128 + wc * 64;   // this wave's B rows
    const int NT = K >> 5;

    f32x4 acc[4][4];
    #pragma unroll
    for (int i = 0; i < 4; i++)
        #pragma unroll
        for (int j = 0; j < 4; j++)
            acc[i][j] = {0.f, 0.f, 0.f, 0.f};

    // stage this wave's 64x32 A and B tiles into private buffer buf.
    // chunk c in [0,256): local row r=c>>2, phys slot c&3 holds logical
    // granule ks = (c&3) ^ ((r>>1)&3); LDS fill is linear (offset c*16 B).
    auto stage = [&](int buf, int k0) {
        #pragma unroll
        for (int i = 0; i < 4; i++) {
            int c = i * 64 + lane;
            int r = c >> 2;
            int ks = (c & 3) ^ ((r >> 1) & 3);
            const ushortT* ga = &A[(size_t)(aRow0 + r) * K + k0 + ks * 8];
            __builtin_amdgcn_global_load_lds((glob_uint*)ga,
                (lds_uint*)&Abuf[w][buf][i * 512], 16, 0, 0);
        }
        #pragma unroll
        for (int i = 0; i < 4; i++) {
            int c = i * 64 + lane;
            int r = c >> 2;
            int ks = (c & 3) ^ ((r >> 1) & 3);
            const ushortT* gb = &Bt[(size_t)(bRow0 + r) * K + k0 + ks * 8];
            __builtin_amdgcn_global_load_lds((glob_uint*)gb,
                (lds_uint*)&Bbuf[w][buf][i * 512], 16, 0, 0);
        }
    };

    stage(0, 0);                                   // 8 loads in flight
    int cur = 0;
    for (int t = 0; t < NT; t++) {
        if (t + 1 < NT) {
            stage(cur ^ 1, (t + 1) * 32);          // +8 -> 16 outstanding
            asm volatile("s_waitcnt vmcnt(8)" ::: "memory");   // cur's 8 landed
        } else {
            asm volatile("s_waitcnt vmcnt(0)" ::: "memory");
        }
        // NO barrier: this wave reads only its own region.
        const char* as = (const char*)&Abuf[w][cur][0];
        const char* bs = (const char*)&Bbuf[w][cur][0];
        short8 af[4], bfr[4];
        #pragma unroll
        for (int i = 0; i < 4; i++) {
            int r = i * 16 + l15;                  // local row 0..63
            int cb = (lg * 16) ^ (((r >> 1) & 3) << 4);
            af[i] = *(const short8*)(as + r * 64 + cb);
        }
        #pragma unroll
        for (int j = 0; j < 4; j++) {
            int r = j * 16 + l15;
            int cb = (lg * 16) ^ (((r >> 1) & 3) << 4);
            bfr[j] = *(const short8*)(bs + r * 64 + cb);
        }
        __builtin_amdgcn_s_setprio(1);
        #pragma unroll
        for (int i = 0; i < 4; i++)
            #pragma unroll
            for (int j = 0; j < 4; j++)
                acc[i][j] = __builtin_amdgcn_mfma_f32_16x16x32_bf16(af[i], bfr[j], acc[i][j], 0, 0, 0);
        __builtin_amdgcn_s_setprio(0);
        cur ^= 1;
    }

    int lr = lg * 4;
    #pragma unroll
    for (int i = 0; i < 4; i++) {
        #pragma unroll
        for (int j = 0; j < 4; j++) {
            int col = bRow0 + j * 16 + l15;
            #pragma unroll
            for (int q = 0; q < 4; q++) {
                size_t row = (size_t)(aRow0 + i * 16 + lr + q);
                float vv = acc[i][j][q] + bias[col];
                vv = fmaxf(vv, 0.f);
                outp[row * N + col] = f2bf(vv);
            }
        }
    }
}

// ---------------------------------------------------------------------------
// BK=64 deep-step GEMM (round-8 proven) for grid-capped N=512 GEMMs (wo, w2).
// +bias, +bf16 residual, bf16 store.
// ---------------------------------------------------------------------------
__global__ __launch_bounds__(256, 2) void gemm_k64_res(const ushortT* __restrict__ A,
                                                       const ushortT* __restrict__ Bt,
                                                       const float* __restrict__ bias,
                                                       const ushortT* __restrict__ res,
                                                       ushortT* __restrict__ outp,
                                                       int N, int K) {
    __shared__ __align__(16) ushortT As[2][128 * 64];
    __shared__ __align__(16) ushortT Bs[2][128 * 64];
    const int tid = threadIdx.x;
    const int w = tid >> 6, lane = tid & 63;
    const int wr = w >> 1, wc = w & 1;
    const int l15 = lane & 15, lg = lane >> 4;
    const int mBase = blockIdx.x * 128, nBase = blockIdx.y * 128;
    const int NT = K >> 6;
    const int srow = lane >> 3;
    const int sgran = lane & 7;

    f32x4 acc[4][4];
    #pragma unroll
    for (int i = 0; i < 4; i++)
        #pragma unroll
        for (int j = 0; j < 4; j++)
            acc[i][j] = {0.f, 0.f, 0.f, 0.f};

    auto stage = [&](int buf, int k0) {
        #pragma unroll
        for (int t = 0; t < 4; t++) {
            int r = w * 32 + t * 8 + srow;
            int gl = sgran ^ (r & 7);
            const ushortT* ga = &A[(size_t)(mBase + r) * K + k0 + gl * 8];
            __builtin_amdgcn_global_load_lds((glob_uint*)ga,
                (lds_uint*)&As[buf][(w * 32 + t * 8) * 64], 16, 0, 0);
            const ushortT* gb = &Bt[(size_t)(nBase + r) * K + k0 + gl * 8];
            __builtin_amdgcn_global_load_lds((glob_uint*)gb,
                (lds_uint*)&Bs[buf][(w * 32 + t * 8) * 64], 16, 0, 0);
        }
    };

    stage(0, 0);
    int cur = 0;
    for (int t = 0; t < NT; t++) {
        asm volatile("s_waitcnt vmcnt(0)" ::: "memory");
        __builtin_amdgcn_s_barrier();
        __builtin_amdgcn_sched_barrier(0);
        if (t + 1 < NT) stage(cur ^ 1, (t + 1) * 64);

        const char* as = (const char*)&As[cur][0];
        const char* bs = (const char*)&Bs[cur][0];
        short8 af[2][4], bfr[2][4];
        #pragma unroll
        for (int i = 0; i < 4; i++) {
            int r = wr * 64 + i * 16 + l15;
            #pragma unroll
            for (int kk = 0; kk < 2; kk++) {
                int g = (kk * 4 + lg) ^ (r & 7);
                af[kk][i] = *(const short8*)(as + r * 128 + g * 16);
            }
        }
        #pragma unroll
        for (int j = 0; j < 4; j++) {
            int r = wc * 64 + j * 16 + l15;
            #pragma unroll
            for (int kk = 0; kk < 2; kk++) {
                int g = (kk * 4 + lg) ^ (r & 7);
                bfr[kk][j] = *(const short8*)(bs + r * 128 + g * 16);
            }
        }
        __builtin_amdgcn_s_setprio(1);
        #pragma unroll
        for (int kk = 0; kk < 2; kk++)
            #pragma unroll
            for (int i = 0; i < 4; i++)
                #pragma unroll
                for (int j = 0; j < 4; j++)
                    acc[i][j] = __builtin_amdgcn_mfma_f32_16x16x32_bf16(af[kk][i], bfr[kk][j], acc[i][j], 0, 0, 0);
        __builtin_amdgcn_s_setprio(0);
        asm volatile("s_waitcnt lgkmcnt(0)" ::: "memory");
        cur ^= 1;
    }

    int lr = lg * 4;
    #pragma unroll
    for (int i = 0; i < 4; i++) {
        #pragma unroll
        for (int j = 0; j < 4; j++) {
            int col = nBase + wc * 64 + j * 16 + l15;
            #pragma unroll
            for (int q = 0; q < 4; q++) {
                size_t row = (size_t)(mBase + wr * 64 + i * 16 + lr + q);
                float vv = acc[i][j][q] + bias[col] + bf2f(res[row * N + col]);
                outp[row * N + col] = f2bf(vv);
            }
        }
    }
}

// ---------------------------------------------------------------------------
// MFMA flash attention with T15 pipeline (round-12 proven).
// ---------------------------------------------------------------------------
__global__ __launch_bounds__(256) void attn_kernel(const ushortT* __restrict__ qp,
                                                   const ushortT* __restrict__ kp,
                                                   const ushortT* __restrict__ vp,
                                                   ushortT* __restrict__ att) {
    __shared__ ushortT K_lds[T_SEQ][72];
    __shared__ ushortT Vt_lds[HS_D][264];
    __shared__ ushortT P_lds[4][16][72];
    int bh = blockIdx.x;
    int b = bh >> 3, h = bh & 7;
    int tid = threadIdx.x;
    int w = tid >> 6, lane = tid & 63;
    const size_t rowbase = (size_t)b * T_SEQ * C_DIM + (size_t)h * HS_D;
    int l15 = lane & 15, lg = lane >> 4;

    #pragma unroll
    for (int it = 0; it < 8; it++) {
        int f = tid + it * 256;
        int r = f >> 3, c8 = f & 7;
        ushort8 kb = *(const ushort8*)&kp[rowbase + (size_t)r * C_DIM + c8 * 8];
        *(ushort8*)&K_lds[r][c8 * 8] = kb;
        ushort8 vb = *(const ushort8*)&vp[rowbase + (size_t)r * C_DIM + c8 * 8];
        #pragma unroll
        for (int e = 0; e < 8; e++) Vt_lds[c8 * 8 + e][r] = vb[e];
    }

    short8 qf[4][2];
    #pragma unroll
    for (int i = 0; i < 4; i++) {
        int grow = 16 * (4 * i + w) + l15;
        #pragma unroll
        for (int kk = 0; kk < 2; kk++)
            qf[i][kk] = *(const short8*)&qp[rowbase + (size_t)grow * C_DIM + kk * 32 + lg * 8];
    }
    __syncthreads();

    f32x4 acc_o[4][4];
    float mrun[4][4], lrun[4][4];
    #pragma unroll
    for (int i = 0; i < 4; i++) {
        #pragma unroll
        for (int j = 0; j < 4; j++) acc_o[i][j] = {0.f, 0.f, 0.f, 0.f};
        #pragma unroll
        for (int q = 0; q < 4; q++) { mrun[i][q] = -1e30f; lrun[i][q] = 0.f; }
    }

    const int UJ[10] = {0,0,0,0, 1,1,1, 2,2, 3};
    const int UI[10] = {0,1,2,3, 1,2,3, 2,3, 3};

    auto qk = [&](int jt, int i, f32x4* dst) {
        #pragma unroll
        for (int j_ = 0; j_ < 4; j_++) dst[j_] = {0.f, 0.f, 0.f, 0.f};
        #pragma unroll
        for (int j_ = 0; j_ < 4; j_++)
            #pragma unroll
            for (int kk = 0; kk < 2; kk++) {
                short8 kf = *(const short8*)&K_lds[jt * 64 + j_ * 16 + l15][kk * 32 + lg * 8];
                dst[j_] = __builtin_amdgcn_mfma_f32_16x16x32_bf16(qf[i][kk], kf, dst[j_], 0, 0, 0);
            }
    };

    f32x4 sCur[4];
    qk(UJ[0], UI[0], sCur);

    #pragma unroll
    for (int u = 0; u < 10; u++) {
        const int jt = UJ[u], i = UI[u];
        f32x4 sNxt[4];
        if (u < 9) qk(UJ[u + 1], UI[u + 1], sNxt);

        float sv[4][4];
        #pragma unroll
        for (int j_ = 0; j_ < 4; j_++) {
            int colg = jt * 64 + j_ * 16 + l15;
            #pragma unroll
            for (int q = 0; q < 4; q++) {
                int rowg = 16 * (4 * i + w) + lg * 4 + q;
                float s = sCur[j_][q] * SM_SCALE;
                sv[j_][q] = (i == jt && colg > rowg) ? -1e30f : s;
            }
        }
        #pragma unroll
        for (int q = 0; q < 4; q++) {
            float mx = fmaxf(fmaxf(sv[0][q], sv[1][q]), fmaxf(sv[2][q], sv[3][q]));
            #pragma unroll
            for (int msk = 1; msk <= 8; msk <<= 1) mx = fmaxf(mx, __shfl_xor(mx, msk, 64));
            float mold = mrun[i][q];
            float mnew = fmaxf(mold, mx);
            float corr = __expf(mold - mnew);
            mrun[i][q] = mnew;
            float ps = 0.f;
            #pragma unroll
            for (int j_ = 0; j_ < 4; j_++) {
                float pe = __expf(sv[j_][q] - mnew);
                ps += pe;
                P_lds[w][lg * 4 + q][j_ * 16 + l15] = f2bf(pe);
            }
            lrun[i][q] = lrun[i][q] * corr + ps;
            #pragma unroll
            for (int dj = 0; dj < 4; dj++) acc_o[i][dj][q] *= corr;
        }
        short8 pa[2];
        #pragma unroll
        for (int kk = 0; kk < 2; kk++)
            pa[kk] = *(const short8*)&P_lds[w][l15][kk * 32 + lg * 8];
        #pragma unroll
        for (int dj = 0; dj < 4; dj++)
            #pragma unroll
            for (int kk = 0; kk < 2; kk++) {
                short8 vf = *(const short8*)&Vt_lds[dj * 16 + l15][jt * 64 + kk * 32 + lg * 8];
                acc_o[i][dj] = __builtin_amdgcn_mfma_f32_16x16x32_bf16(pa[kk], vf, acc_o[i][dj], 0, 0, 0);
            }
        if (u < 9) {
            #pragma unroll
            for (int j_ = 0; j_ < 4; j_++) sCur[j_] = sNxt[j_];
        }
    }

    #pragma unroll
    for (int i = 0; i < 4; i++) {
        float inv[4];
        #pragma unroll
        for (int q = 0; q < 4; q++) {
            float ls = lrun[i][q];
            #pragma unroll
            for (int msk = 1; msk <= 8; msk <<= 1) ls += __shfl_xor(ls, msk, 64);
            inv[q] = 1.0f / ls;
        }
        #pragma unroll
        for (int dj = 0; dj < 4; dj++) {
            int colg = dj * 16 + l15;
            #pragma unroll
            for (int q = 0; q < 4; q++) {
                int rowg = 16 * (4 * i + w) + lg * 4 + q;
                att[rowbase + (size_t)rowg * C_DIM + colg] = f2bf(acc_o[i][dj][q] * inv[q]);
            }
        }
    }
}

// ---------------------------------------------------------------------------
// Loss
// ---------------------------------------------------------------------------
__global__ __launch_bounds__(256) void rowloss_kernel(const float* __restrict__ logits,
                                                      const int* __restrict__ tgt,
                                                      float* __restrict__ rl) {
    int wave = threadIdx.x >> 6, lane = threadIdx.x & 63;
    int n = blockIdx.x * 4 + wave;
    const float* l = logits + (size_t)n * V_SZ;
    float v0 = l[lane];
    float v1 = (lane == 0) ? l[64] : -1e30f;
    float m = fmaxf(v0, v1);
    #pragma unroll
    for (int s = 32; s >= 1; s >>= 1) m = fmaxf(m, __shfl_xor(m, s, 64));
    float e = __expf(v0 - m) + ((lane == 0) ? __expf(v1 - m) : 0.f);
    #pragma unroll
    for (int s = 32; s >= 1; s >>= 1) e += __shfl_xor(e, s, 64);
    if (lane == 0) {
        float lp = l[tgt[n]] - m - logf(e);
        rl[n] = -lp;
    }
}

__global__ __launch_bounds__(256) void reduce_loss_kernel(const float* __restrict__ rl,
                                                          float* __restrict__ out_loss) {
    __shared__ float sdata[256];
    float s = 0.f;
    for (int i = threadIdx.x; i < N_TOK; i += 256) s += rl[i];
    sdata[threadIdx.x] = s;
    __syncthreads();
    for (int st = 128; st > 0; st >>= 1) {
        if (threadIdx.x < st) sdata[threadIdx.x] += sdata[threadIdx.x + st];
        __syncthreads();
    }
    if (threadIdx.x == 0) out_loss[0] = sdata[0] * (1.0f / N_TOK);
}

// ---------------------------------------------------------------------------
extern "C" void kernel_launch(void* const* d_in, const int* in_sizes, int n_in,
                              void* d_out, int out_size, void* d_ws, size_t ws_size,
                              hipStream_t stream) {
    const int*   idx     = (const int*)d_in[0];
    const int*   targets = (const int*)d_in[1];
    const float* tok_emb = (const float*)d_in[2];
    const float* pos_emb = (const float*)d_in[3];
    const float* ln1_g   = (const float*)d_in[4];
    const float* ln1_b   = (const float*)d_in[5];
    const float* wq      = (const float*)d_in[6];
    const float* wk      = (const float*)d_in[7];
    const float* wv      = (const float*)d_in[8];
    const float* wo      = (const float*)d_in[9];
    const float* bo      = (const float*)d_in[10];
    const float* ln2_g   = (const float*)d_in[11];
    const float* ln2_b   = (const float*)d_in[12];
    const float* w1      = (const float*)d_in[13];
    const float* b1      = (const float*)d_in[14];
    const float* w2      = (const float*)d_in[15];
    const float* b2      = (const float*)d_in[16];
    const float* lnf_g   = (const float*)d_in[17];
    const float* lnf_b   = (const float*)d_in[18];
    const float* lm_w    = (const float*)d_in[19];
    const float* lm_b    = (const float*)d_in[20];

    float* out = (float*)d_out;
    char*  ws  = (char*)d_ws;
    const size_t MB = 1024ull * 1024ull;
    ushortT* x_bf  = (ushortT*)(ws);             // 0..16   bf16 residual
    ushortT* h_bf  = (ushortT*)(ws + 32 * MB);   // 32..48  bf16 LN out
    ushortT* q_bf  = (ushortT*)(ws + 48 * MB);   // 48..64
    ushortT* k_bf  = (ushortT*)(ws + 64 * MB);   // 64..80
    ushortT* v_bf  = (ushortT*)(ws + 80 * MB);   // 80..96
    ushortT* att_bf= (ushortT*)(ws + 112 * MB);  // 112..128
    ushortT* ff1_bf= (ushortT*)(ws + 48 * MB);   // 48..112 (reuses q/k/v)
    ushortT* wqT   = (ushortT*)(ws + 128 * MB);
    ushortT* wkT   = (ushortT*)(ws + 132 * MB);
    ushortT* wvT   = (ushortT*)(ws + 136 * MB);
    ushortT* woT   = (ushortT*)(ws + 140 * MB);
    ushortT* w1T   = (ushortT*)(ws + 144 * MB);  // 16MB
    ushortT* w2T   = (ushortT*)(ws + 160 * MB);  // 16MB
    float*   rl    = (float*)(ws + 176 * MB);    // 64KB
    ushortT* lmT   = (ushortT*)(ws + 177 * MB);  // 128KB

    {
        dim3 gCC(C_DIM / 32, C_DIM / 32, L_N);
        tcast_kernel<<<gCC, 256, 0, stream>>>(wq, wqT, C_DIM, C_DIM);
        tcast_kernel<<<gCC, 256, 0, stream>>>(wk, wkT, C_DIM, C_DIM);
        tcast_kernel<<<gCC, 256, 0, stream>>>(wv, wvT, C_DIM, C_DIM);
        tcast_kernel<<<gCC, 256, 0, stream>>>(wo, woT, C_DIM, C_DIM);
        dim3 g1(4 * C_DIM / 32, C_DIM / 32, L_N);
        tcast_kernel<<<g1, 256, 0, stream>>>(w1, w1T, C_DIM, 4 * C_DIM);
        dim3 g2(C_DIM / 32, 4 * C_DIM / 32, L_N);
        tcast_kernel<<<g2, 256, 0, stream>>>(w2, w2T, 4 * C_DIM, C_DIM);
        lmcast_kernel<<<128, 256, 0, stream>>>(lm_w, lmT);
    }

    embed_kernel<<<(N_TOK * C_DIM / 8 + 255) / 256, 256, 0, stream>>>(idx, tok_emb, pos_emb, x_bf);

    dim3 gemmCC(N_TOK / 128, C_DIM / 128);          // (128, 4)
    dim3 gemmW1(N_TOK / 128, 4 * C_DIM / 128);      // (128, 16)
    dim3 gemmQKV(N_TOK / 128, C_DIM / 128, 3);      // (128, 4, 3)

    for (int l = 0; l < L_N; l++) {
        const ushortT* wqT_l = wqT + (size_t)l * C_DIM * C_DIM;
        const ushortT* wkT_l = wkT + (size_t)l * C_DIM * C_DIM;
        const ushortT* wvT_l = wvT + (size_t)l * C_DIM * C_DIM;
        const ushortT* woT_l = woT + (size_t)l * C_DIM * C_DIM;
        const ushortT* w1T_l = w1T + (size_t)l * C_DIM * 4 * C_DIM;
        const ushortT* w2T_l = w2T + (size_t)l * C_DIM * 4 * C_DIM;

        ln_kernel<<<N_TOK / 4, 256, 0, stream>>>(x_bf, ln1_g + l * C_DIM, ln1_b + l * C_DIM, h_bf);
        gemm_qkv<<<gemmQKV, 256, 0, stream>>>(h_bf, wqT_l, wkT_l, wvT_l, q_bf, k_bf, v_bf, C_DIM, C_DIM);
        attn_kernel<<<64 * H_N, 256, 0, stream>>>(q_bf, k_bf, v_bf, att_bf);
        gemm_k64_res<<<gemmCC, 256, 0, stream>>>(att_bf, woT_l, bo + l * C_DIM, x_bf, x_bf, C_DIM, C_DIM);
        ln_kernel<<<N_TOK / 4, 256, 0, stream>>>(x_bf, ln2_g + l * C_DIM, ln2_b + l * C_DIM, h_bf);
        gemm_nobar<<<gemmW1, 256, 0, stream>>>(h_bf, w1T_l, b1 + (size_t)l * 4 * C_DIM, ff1_bf, 4 * C_DIM, C_DIM);
        gemm_k64_res<<<gemmCC, 256, 0, stream>>>(ff1_bf, w2T_l, b2 + l * C_DIM, x_bf, x_bf, C_DIM, 4 * C_DIM);
    }

    // final LN (bf16) + MFMA LM head -> f32 logits
    ln_kernel<<<N_TOK / 4, 256, 0, stream>>>(x_bf, lnf_g, lnf_b, h_bf);
    gemm_bf16<4><<<dim3(N_TOK / 128, 1), 256, 0, stream>>>(h_bf, lmT, lm_b, out, V_SZ, C_DIM);

    rowloss_kernel<<<N_TOK / 4, 256, 0, stream>>>(out, targets, rl);
    reduce_loss_kernel<<<1, 256, 0, stream>>>(rl, out + (size_t)N_TOK * V_SZ);
}

// Round 15
// 1542.640 us; speedup vs baseline: 1.0809x; 1.0809x over previous
//
#include <hip/hip_runtime.h>
#include <math.h>

#define V_SZ   65
#define C_DIM  512
#define T_SEQ  256
#define H_N    8
#define HS_D   64
#define L_N    8
#define N_TOK  16384   // B*T = 64*256
#define LN_EPS 1e-5f
#define SM_SCALE 0.044194173824159216f  // 512^-0.5 (scaled by n_embd, per reference)

typedef unsigned short ushortT;
typedef __attribute__((ext_vector_type(8))) short    short8;
typedef __attribute__((ext_vector_type(8))) ushortT  ushort8;
typedef __attribute__((ext_vector_type(4))) float    f32x4;

typedef __attribute__((address_space(3))) unsigned int        lds_uint;
typedef const __attribute__((address_space(1))) unsigned int  glob_uint;

__device__ inline ushortT f2bf(float f) {
    unsigned int u = __float_as_uint(f);
    u = (u + 0x7fffu + ((u >> 16) & 1u)) >> 16;   // RNE
    return (ushortT)u;
}
__device__ inline float bf2f(ushortT u) {
    return __uint_as_float(((unsigned int)u) << 16);
}

// ---------------------------------------------------------------------------
// Embedding -> bf16 residual stream (sum computed fp32, rounded once)
// ---------------------------------------------------------------------------
__global__ void embed_kernel(const int* __restrict__ idx,
                             const float* __restrict__ tok,
                             const float* __restrict__ pos,
                             ushortT* __restrict__ x) {
    int i = blockIdx.x * blockDim.x + threadIdx.x;   // 8-elem chunk index
    const int NC8 = N_TOK * C_DIM / 8;
    if (i >= NC8) return;
    int c8 = i % (C_DIM / 8);
    int n  = i / (C_DIM / 8);
    int t  = n % T_SEQ;
    int tk = idx[n];
    const float4* ta = (const float4*)&tok[(size_t)tk * C_DIM + c8 * 8];
    const float4* pa = (const float4*)&pos[(size_t)t  * C_DIM + c8 * 8];
    float4 a0 = ta[0], a1 = ta[1], p0 = pa[0], p1 = pa[1];
    ushort8 r;
    r[0] = f2bf(a0.x + p0.x); r[1] = f2bf(a0.y + p0.y);
    r[2] = f2bf(a0.z + p0.z); r[3] = f2bf(a0.w + p0.w);
    r[4] = f2bf(a1.x + p1.x); r[5] = f2bf(a1.y + p1.y);
    r[6] = f2bf(a1.z + p1.z); r[7] = f2bf(a1.w + p1.w);
    *(ushort8*)&x[(size_t)i * 8] = r;
}

// ---------------------------------------------------------------------------
// Weight transpose+cast: src[K][N] f32 -> dst[N][K] bf16, batched over L.
// ---------------------------------------------------------------------------
__global__ __launch_bounds__(256) void tcast_kernel(const float* __restrict__ src,
                                                    ushortT* __restrict__ dst,
                                                    int K, int N) {
    __shared__ float tile[32][33];
    size_t lo = (size_t)blockIdx.z * K * N;
    int n0 = blockIdx.x * 32, k0 = blockIdx.y * 32;
    int tx = threadIdx.x & 31, ty = threadIdx.x >> 5;
    #pragma unroll
    for (int s = 0; s < 4; s++) {
        int kk = ty + s * 8;
        tile[kk][tx] = src[lo + (size_t)(k0 + kk) * N + n0 + tx];
    }
    __syncthreads();
    #pragma unroll
    for (int s = 0; s < 4; s++) {
        int nn = ty + s * 8;
        dst[lo + (size_t)(n0 + nn) * K + k0 + tx] = f2bf(tile[tx][nn]);
    }
}

// lm head weight: lm_w[512][65] f32 -> lmT[128][512] bf16 (rows >=65 zero)
__global__ __launch_bounds__(256) void lmcast_kernel(const float* __restrict__ w,
                                                     ushortT* __restrict__ dst) {
    int n = blockIdx.x;            // 0..127
    for (int k = threadIdx.x; k < C_DIM; k += 256)
        dst[(size_t)n * C_DIM + k] = (n < V_SZ) ? f2bf(w[(size_t)k * V_SZ + n]) : (ushortT)0;
}

// ---------------------------------------------------------------------------
// LayerNorm: one wave per row of C=512, bf16 in/out, fp32 stats.
// ---------------------------------------------------------------------------
__global__ __launch_bounds__(256) void ln_kernel(const ushortT* __restrict__ in,
                                                 const float* __restrict__ g,
                                                 const float* __restrict__ b,
                                                 ushortT* __restrict__ outv) {
    int wave = threadIdx.x >> 6;
    int lane = threadIdx.x & 63;
    int row  = blockIdx.x * 4 + wave;
    ushort8 raw = *(const ushort8*)&in[(size_t)row * C_DIM + lane * 8];
    float v[8];
    #pragma unroll
    for (int k = 0; k < 8; k++) v[k] = bf2f(raw[k]);
    float s = 0.f;
    #pragma unroll
    for (int k = 0; k < 8; k++) s += v[k];
    #pragma unroll
    for (int m = 32; m >= 1; m >>= 1) s += __shfl_xor(s, m, 64);
    float mean = s * (1.0f / C_DIM);
    float vs = 0.f;
    #pragma unroll
    for (int k = 0; k < 8; k++) { float d = v[k] - mean; vs += d * d; }
    #pragma unroll
    for (int m = 32; m >= 1; m >>= 1) vs += __shfl_xor(vs, m, 64);
    float rstd = rsqrtf(vs * (1.0f / C_DIM) + LN_EPS);
    float gv[8], bv[8];
    *(float4*)&gv[0] = *(const float4*)&g[lane * 8];
    *(float4*)&gv[4] = *(const float4*)&g[lane * 8 + 4];
    *(float4*)&bv[0] = *(const float4*)&b[lane * 8];
    *(float4*)&bv[4] = *(const float4*)&b[lane * 8 + 4];
    ushort8 pack;
    #pragma unroll
    for (int k = 0; k < 8; k++) pack[k] = f2bf((v[k] - mean) * rstd * gv[k] + bv[k]);
    *(ushort8*)&outv[(size_t)row * C_DIM + lane * 8] = pack;
}

// ---------------------------------------------------------------------------
// ROUND-4 PROVEN bf16 MFMA GEMM core (BK=32). qkv / w1 / lm head.
// EPI: 1 bf16 | 2 +bias,relu -> bf16 | 4 lm head f32
// ---------------------------------------------------------------------------
template<int EPI>
__device__ __forceinline__ void gemm_core(const ushortT* __restrict__ A,
                                          const ushortT* __restrict__ Bt,
                                          const float* __restrict__ bias,
                                          void* __restrict__ outp,
                                          int N, int K,
                                          int mBase, int nBase) {
    __shared__ __align__(16) ushortT As[128 * 32];
    __shared__ __align__(16) ushortT Bs[128 * 32];
    const int tid = threadIdx.x;
    const int w = tid >> 6, lane = tid & 63;
    const int wr = w >> 1, wc = w & 1;
    const int l15 = lane & 15, lg = lane >> 4;
    const int srow = (lane >> 2);
    const int sslot = lane & 3;

    f32x4 acc[4][4];
    #pragma unroll
    for (int i = 0; i < 4; i++)
        #pragma unroll
        for (int j = 0; j < 4; j++)
            acc[i][j] = {0.f, 0.f, 0.f, 0.f};

    for (int k0 = 0; k0 < K; k0 += 32) {
        #pragma unroll
        for (int t = 0; t < 2; t++) {
            int r = w * 32 + t * 16 + srow;
            int ks = sslot ^ ((r >> 1) & 3);
            const ushortT* ga = &A[(size_t)(mBase + r) * K + k0 + ks * 8];
            __builtin_amdgcn_global_load_lds((glob_uint*)ga,
                (lds_uint*)&As[(w * 32 + t * 16) * 32], 16, 0, 0);
            const ushortT* gb = &Bt[(size_t)(nBase + r) * K + k0 + ks * 8];
            __builtin_amdgcn_global_load_lds((glob_uint*)gb,
                (lds_uint*)&Bs[(w * 32 + t * 16) * 32], 16, 0, 0);
        }
        __syncthreads();
        short8 af[4], bfr[4];
        #pragma unroll
        for (int i = 0; i < 4; i++) {
            int r = wr * 64 + i * 16 + l15;
            int cb = (lg * 16) ^ (((r >> 1) & 3) << 4);
            af[i] = *(const short8*)((const char*)As + r * 64 + cb);
        }
        #pragma unroll
        for (int j = 0; j < 4; j++) {
            int r = wc * 64 + j * 16 + l15;
            int cb = (lg * 16) ^ (((r >> 1) & 3) << 4);
            bfr[j] = *(const short8*)((const char*)Bs + r * 64 + cb);
        }
        #pragma unroll
        for (int i = 0; i < 4; i++)
            #pragma unroll
            for (int j = 0; j < 4; j++)
                acc[i][j] = __builtin_amdgcn_mfma_f32_16x16x32_bf16(af[i], bfr[j], acc[i][j], 0, 0, 0);
        __syncthreads();
    }

    int lr = lg * 4;
    #pragma unroll
    for (int i = 0; i < 4; i++) {
        #pragma unroll
        for (int j = 0; j < 4; j++) {
            int col = nBase + wc * 64 + j * 16 + l15;
            if (EPI == 4 && col >= V_SZ) continue;
            #pragma unroll
            for (int q = 0; q < 4; q++) {
                size_t row = (size_t)(mBase + wr * 64 + i * 16 + lr + q);
                float vv = acc[i][j][q];
                if (EPI >= 2) vv += bias[col];
                if (EPI == 2) vv = fmaxf(vv, 0.f);
                if (EPI == 1)      ((ushortT*)outp)[row * N + col] = f2bf(vv);
                else if (EPI == 2) ((ushortT*)outp)[row * N + col] = f2bf(vv);
                else               ((float*)outp)[row * V_SZ + col] = vv;   // EPI 4
            }
        }
    }
}

template<int EPI>
__global__ __launch_bounds__(256, 2) void gemm_bf16(const ushortT* __restrict__ A,
                                                    const ushortT* __restrict__ Bt,
                                                    const float* __restrict__ bias,
                                                    void* __restrict__ outp,
                                                    int N, int K) {
    gemm_core<EPI>(A, Bt, bias, outp, N, K, blockIdx.x * 128, blockIdx.y * 128);
}

__global__ __launch_bounds__(256, 2) void gemm_qkv(const ushortT* __restrict__ A,
                                                   const ushortT* __restrict__ bq,
                                                   const ushortT* __restrict__ bk,
                                                   const ushortT* __restrict__ bv,
                                                   ushortT* __restrict__ oq,
                                                   ushortT* __restrict__ ok,
                                                   ushortT* __restrict__ ov,
                                                   int N, int K) {
    const ushortT* Bt = (blockIdx.z == 0) ? bq : (blockIdx.z == 1) ? bk : bv;
    ushortT*       o  = (blockIdx.z == 0) ? oq : (blockIdx.z == 1) ? ok : ov;
    gemm_core<1>(A, Bt, nullptr, o, N, K, blockIdx.x * 128, blockIdx.y * 128);
}

// ---------------------------------------------------------------------------
// BK=64 deep-step GEMM (round-8 proven) for grid-capped N=512 GEMMs (wo, w2).
// +bias, +bf16 residual, bf16 store.
// ---------------------------------------------------------------------------
__global__ __launch_bounds__(256, 2) void gemm_k64_res(const ushortT* __restrict__ A,
                                                       const ushortT* __restrict__ Bt,
                                                       const float* __restrict__ bias,
                                                       const ushortT* __restrict__ res,
                                                       ushortT* __restrict__ outp,
                                                       int N, int K) {
    __shared__ __align__(16) ushortT As[2][128 * 64];
    __shared__ __align__(16) ushortT Bs[2][128 * 64];
    const int tid = threadIdx.x;
    const int w = tid >> 6, lane = tid & 63;
    const int wr = w >> 1, wc = w & 1;
    const int l15 = lane & 15, lg = lane >> 4;
    const int mBase = blockIdx.x * 128, nBase = blockIdx.y * 128;
    const int NT = K >> 6;
    const int srow = lane >> 3;
    const int sgran = lane & 7;

    f32x4 acc[4][4];
    #pragma unroll
    for (int i = 0; i < 4; i++)
        #pragma unroll
        for (int j = 0; j < 4; j++)
            acc[i][j] = {0.f, 0.f, 0.f, 0.f};

    auto stage = [&](int buf, int k0) {
        #pragma unroll
        for (int t = 0; t < 4; t++) {
            int r = w * 32 + t * 8 + srow;
            int gl = sgran ^ (r & 7);
            const ushortT* ga = &A[(size_t)(mBase + r) * K + k0 + gl * 8];
            __builtin_amdgcn_global_load_lds((glob_uint*)ga,
                (lds_uint*)&As[buf][(w * 32 + t * 8) * 64], 16, 0, 0);
            const ushortT* gb = &Bt[(size_t)(nBase + r) * K + k0 + gl * 8];
            __builtin_amdgcn_global_load_lds((glob_uint*)gb,
                (lds_uint*)&Bs[buf][(w * 32 + t * 8) * 64], 16, 0, 0);
        }
    };

    stage(0, 0);
    int cur = 0;
    for (int t = 0; t < NT; t++) {
        asm volatile("s_waitcnt vmcnt(0)" ::: "memory");
        __builtin_amdgcn_s_barrier();
        __builtin_amdgcn_sched_barrier(0);
        if (t + 1 < NT) stage(cur ^ 1, (t + 1) * 64);

        const char* as = (const char*)&As[cur][0];
        const char* bs = (const char*)&Bs[cur][0];
        short8 af[2][4], bfr[2][4];
        #pragma unroll
        for (int i = 0; i < 4; i++) {
            int r = wr * 64 + i * 16 + l15;
            #pragma unroll
            for (int kk = 0; kk < 2; kk++) {
                int g = (kk * 4 + lg) ^ (r & 7);
                af[kk][i] = *(const short8*)(as + r * 128 + g * 16);
            }
        }
        #pragma unroll
        for (int j = 0; j < 4; j++) {
            int r = wc * 64 + j * 16 + l15;
            #pragma unroll
            for (int kk = 0; kk < 2; kk++) {
                int g = (kk * 4 + lg) ^ (r & 7);
                bfr[kk][j] = *(const short8*)(bs + r * 128 + g * 16);
            }
        }
        __builtin_amdgcn_s_setprio(1);
        #pragma unroll
        for (int kk = 0; kk < 2; kk++)
            #pragma unroll
            for (int i = 0; i < 4; i++)
                #pragma unroll
                for (int j = 0; j < 4; j++)
                    acc[i][j] = __builtin_amdgcn_mfma_f32_16x16x32_bf16(af[kk][i], bfr[kk][j], acc[i][j], 0, 0, 0);
        __builtin_amdgcn_s_setprio(0);
        asm volatile("s_waitcnt lgkmcnt(0)" ::: "memory");
        cur ^= 1;
    }

    int lr = lg * 4;
    #pragma unroll
    for (int i = 0; i < 4; i++) {
        #pragma unroll
        for (int j = 0; j < 4; j++) {
            int col = nBase + wc * 64 + j * 16 + l15;
            #pragma unroll
            for (int q = 0; q < 4; q++) {
                size_t row = (size_t)(mBase + wr * 64 + i * 16 + lr + q);
                float vv = acc[i][j][q] + bias[col] + bf2f(res[row * N + col]);
                outp[row * N + col] = f2bf(vv);
            }
        }
    }
}

// ---------------------------------------------------------------------------
// MFMA flash attention with T15 pipeline (round-12 proven).
// ---------------------------------------------------------------------------
__global__ __launch_bounds__(256) void attn_kernel(const ushortT* __restrict__ qp,
                                                   const ushortT* __restrict__ kp,
                                                   const ushortT* __restrict__ vp,
                                                   ushortT* __restrict__ att) {
    __shared__ ushortT K_lds[T_SEQ][72];
    __shared__ ushortT Vt_lds[HS_D][264];
    __shared__ ushortT P_lds[4][16][72];
    int bh = blockIdx.x;
    int b = bh >> 3, h = bh & 7;
    int tid = threadIdx.x;
    int w = tid >> 6, lane = tid & 63;
    const size_t rowbase = (size_t)b * T_SEQ * C_DIM + (size_t)h * HS_D;
    int l15 = lane & 15, lg = lane >> 4;

    #pragma unroll
    for (int it = 0; it < 8; it++) {
        int f = tid + it * 256;
        int r = f >> 3, c8 = f & 7;
        ushort8 kb = *(const ushort8*)&kp[rowbase + (size_t)r * C_DIM + c8 * 8];
        *(ushort8*)&K_lds[r][c8 * 8] = kb;
        ushort8 vb = *(const ushort8*)&vp[rowbase + (size_t)r * C_DIM + c8 * 8];
        #pragma unroll
        for (int e = 0; e < 8; e++) Vt_lds[c8 * 8 + e][r] = vb[e];
    }

    short8 qf[4][2];
    #pragma unroll
    for (int i = 0; i < 4; i++) {
        int grow = 16 * (4 * i + w) + l15;
        #pragma unroll
        for (int kk = 0; kk < 2; kk++)
            qf[i][kk] = *(const short8*)&qp[rowbase + (size_t)grow * C_DIM + kk * 32 + lg * 8];
    }
    __syncthreads();

    f32x4 acc_o[4][4];
    float mrun[4][4], lrun[4][4];
    #pragma unroll
    for (int i = 0; i < 4; i++) {
        #pragma unroll
        for (int j = 0; j < 4; j++) acc_o[i][j] = {0.f, 0.f, 0.f, 0.f};
        #pragma unroll
        for (int q = 0; q < 4; q++) { mrun[i][q] = -1e30f; lrun[i][q] = 0.f; }
    }

    const int UJ[10] = {0,0,0,0, 1,1,1, 2,2, 3};
    const int UI[10] = {0,1,2,3, 1,2,3, 2,3, 3};

    auto qk = [&](int jt, int i, f32x4* dst) {
        #pragma unroll
        for (int j_ = 0; j_ < 4; j_++) dst[j_] = {0.f, 0.f, 0.f, 0.f};
        #pragma unroll
        for (int j_ = 0; j_ < 4; j_++)
            #pragma unroll
            for (int kk = 0; kk < 2; kk++) {
                short8 kf = *(const short8*)&K_lds[jt * 64 + j_ * 16 + l15][kk * 32 + lg * 8];
                dst[j_] = __builtin_amdgcn_mfma_f32_16x16x32_bf16(qf[i][kk], kf, dst[j_], 0, 0, 0);
            }
    };

    f32x4 sCur[4];
    qk(UJ[0], UI[0], sCur);

    #pragma unroll
    for (int u = 0; u < 10; u++) {
        const int jt = UJ[u], i = UI[u];
        f32x4 sNxt[4];
        if (u < 9) qk(UJ[u + 1], UI[u + 1], sNxt);

        float sv[4][4];
        #pragma unroll
        for (int j_ = 0; j_ < 4; j_++) {
            int colg = jt * 64 + j_ * 16 + l15;
            #pragma unroll
            for (int q = 0; q < 4; q++) {
                int rowg = 16 * (4 * i + w) + lg * 4 + q;
                float s = sCur[j_][q] * SM_SCALE;
                sv[j_][q] = (i == jt && colg > rowg) ? -1e30f : s;
            }
        }
        #pragma unroll
        for (int q = 0; q < 4; q++) {
            float mx = fmaxf(fmaxf(sv[0][q], sv[1][q]), fmaxf(sv[2][q], sv[3][q]));
            #pragma unroll
            for (int msk = 1; msk <= 8; msk <<= 1) mx = fmaxf(mx, __shfl_xor(mx, msk, 64));
            float mold = mrun[i][q];
            float mnew = fmaxf(mold, mx);
            float corr = __expf(mold - mnew);
            mrun[i][q] = mnew;
            float ps = 0.f;
            #pragma unroll
            for (int j_ = 0; j_ < 4; j_++) {
                float pe = __expf(sv[j_][q] - mnew);
                ps += pe;
                P_lds[w][lg * 4 + q][j_ * 16 + l15] = f2bf(pe);
            }
            lrun[i][q] = lrun[i][q] * corr + ps;
            #pragma unroll
            for (int dj = 0; dj < 4; dj++) acc_o[i][dj][q] *= corr;
        }
        short8 pa[2];
        #pragma unroll
        for (int kk = 0; kk < 2; kk++)
            pa[kk] = *(const short8*)&P_lds[w][l15][kk * 32 + lg * 8];
        #pragma unroll
        for (int dj = 0; dj < 4; dj++)
            #pragma unroll
            for (int kk = 0; kk < 2; kk++) {
                short8 vf = *(const short8*)&Vt_lds[dj * 16 + l15][jt * 64 + kk * 32 + lg * 8];
                acc_o[i][dj] = __builtin_amdgcn_mfma_f32_16x16x32_bf16(pa[kk], vf, acc_o[i][dj], 0, 0, 0);
            }
        if (u < 9) {
            #pragma unroll
            for (int j_ = 0; j_ < 4; j_++) sCur[j_] = sNxt[j_];
        }
    }

    #pragma unroll
    for (int i = 0; i < 4; i++) {
        float inv[4];
        #pragma unroll
        for (int q = 0; q < 4; q++) {
            float ls = lrun[i][q];
            #pragma unroll
            for (int msk = 1; msk <= 8; msk <<= 1) ls += __shfl_xor(ls, msk, 64);
            inv[q] = 1.0f / ls;
        }
        #pragma unroll
        for (int dj = 0; dj < 4; dj++) {
            int colg = dj * 16 + l15;
            #pragma unroll
            for (int q = 0; q < 4; q++) {
                int rowg = 16 * (4 * i + w) + lg * 4 + q;
                att[rowbase + (size_t)rowg * C_DIM + colg] = f2bf(acc_o[i][dj][q] * inv[q]);
            }
        }
    }
}

// ---------------------------------------------------------------------------
// Loss
// ---------------------------------------------------------------------------
__global__ __launch_bounds__(256) void rowloss_kernel(const float* __restrict__ logits,
                                                      const int* __restrict__ tgt,
                                                      float* __restrict__ rl) {
    int wave = threadIdx.x >> 6, lane = threadIdx.x & 63;
    int n = blockIdx.x * 4 + wave;
    const float* l = logits + (size_t)n * V_SZ;
    float v0 = l[lane];
    float v1 = (lane == 0) ? l[64] : -1e30f;
    float m = fmaxf(v0, v1);
    #pragma unroll
    for (int s = 32; s >= 1; s >>= 1) m = fmaxf(m, __shfl_xor(m, s, 64));
    float e = __expf(v0 - m) + ((lane == 0) ? __expf(v1 - m) : 0.f);
    #pragma unroll
    for (int s = 32; s >= 1; s >>= 1) e += __shfl_xor(e, s, 64);
    if (lane == 0) {
        float lp = l[tgt[n]] - m - logf(e);
        rl[n] = -lp;
    }
}

__global__ __launch_bounds__(256) void reduce_loss_kernel(const float* __restrict__ rl,
                                                          float* __restrict__ out_loss) {
    __shared__ float sdata[256];
    float s = 0.f;
    for (int i = threadIdx.x; i < N_TOK; i += 256) s += rl[i];
    sdata[threadIdx.x] = s;
    __syncthreads();
    for (int st = 128; st > 0; st >>= 1) {
        if (threadIdx.x < st) sdata[threadIdx.x] += sdata[threadIdx.x + st];
        __syncthreads();
    }
    if (threadIdx.x == 0) out_loss[0] = sdata[0] * (1.0f / N_TOK);
}

// ---------------------------------------------------------------------------
extern "C" void kernel_launch(void* const* d_in, const int* in_sizes, int n_in,
                              void* d_out, int out_size, void* d_ws, size_t ws_size,
                              hipStream_t stream) {
    const int*   idx     = (const int*)d_in[0];
    const int*   targets = (const int*)d_in[1];
    const float* tok_emb = (const float*)d_in[2];
    const float* pos_emb = (const float*)d_in[3];
    const float* ln1_g   = (const float*)d_in[4];
    const float* ln1_b   = (const float*)d_in[5];
    const float* wq      = (const float*)d_in[6];
    const float* wk      = (const float*)d_in[7];
    const float* wv      = (const float*)d_in[8];
    const float* wo      = (const float*)d_in[9];
    const float* bo      = (const float*)d_in[10];
    const float* ln2_g   = (const float*)d_in[11];
    const float* ln2_b   = (const float*)d_in[12];
    const float* w1      = (const float*)d_in[13];
    const float* b1      = (const float*)d_in[14];
    const float* w2      = (const float*)d_in[15];
    const float* b2      = (const float*)d_in[16];
    const float* lnf_g   = (const float*)d_in[17];
    const float* lnf_b   = (const float*)d_in[18];
    const float* lm_w    = (const float*)d_in[19];
    const float* lm_b    = (const float*)d_in[20];

    float* out = (float*)d_out;
    char*  ws  = (char*)d_ws;
    const size_t MB = 1024ull * 1024ull;
    ushortT* x_bf  = (ushortT*)(ws);             // 0..16   bf16 residual
    ushortT* h_bf  = (ushortT*)(ws + 32 * MB);   // 32..48  bf16 LN out
    ushortT* q_bf  = (ushortT*)(ws + 48 * MB);   // 48..64
    ushortT* k_bf  = (ushortT*)(ws + 64 * MB);   // 64..80
    ushortT* v_bf  = (ushortT*)(ws + 80 * MB);   // 80..96
    ushortT* att_bf= (ushortT*)(ws + 112 * MB);  // 112..128
    ushortT* ff1_bf= (ushortT*)(ws + 48 * MB);   // 48..112 (reuses q/k/v)
    ushortT* wqT   = (ushortT*)(ws + 128 * MB);
    ushortT* wkT   = (ushortT*)(ws + 132 * MB);
    ushortT* wvT   = (ushortT*)(ws + 136 * MB);
    ushortT* woT   = (ushortT*)(ws + 140 * MB);
    ushortT* w1T   = (ushortT*)(ws + 144 * MB);  // 16MB
    ushortT* w2T   = (ushortT*)(ws + 160 * MB);  // 16MB
    float*   rl    = (float*)(ws + 176 * MB);    // 64KB
    ushortT* lmT   = (ushortT*)(ws + 177 * MB);  // 128KB

    {
        dim3 gCC(C_DIM / 32, C_DIM / 32, L_N);
        tcast_kernel<<<gCC, 256, 0, stream>>>(wq, wqT, C_DIM, C_DIM);
        tcast_kernel<<<gCC, 256, 0, stream>>>(wk, wkT, C_DIM, C_DIM);
        tcast_kernel<<<gCC, 256, 0, stream>>>(wv, wvT, C_DIM, C_DIM);
        tcast_kernel<<<gCC, 256, 0, stream>>>(wo, woT, C_DIM, C_DIM);
        dim3 g1(4 * C_DIM / 32, C_DIM / 32, L_N);
        tcast_kernel<<<g1, 256, 0, stream>>>(w1, w1T, C_DIM, 4 * C_DIM);
        dim3 g2(C_DIM / 32, 4 * C_DIM / 32, L_N);
        tcast_kernel<<<g2, 256, 0, stream>>>(w2, w2T, 4 * C_DIM, C_DIM);
        lmcast_kernel<<<128, 256, 0, stream>>>(lm_w, lmT);
    }

    embed_kernel<<<(N_TOK * C_DIM / 8 + 255) / 256, 256, 0, stream>>>(idx, tok_emb, pos_emb, x_bf);

    dim3 gemmCC(N_TOK / 128, C_DIM / 128);          // (128, 4)
    dim3 gemmC4(N_TOK / 128, 4 * C_DIM / 128);      // (128, 16)
    dim3 gemmQKV(N_TOK / 128, C_DIM / 128, 3);      // (128, 4, 3)

    for (int l = 0; l < L_N; l++) {
        const ushortT* wqT_l = wqT + (size_t)l * C_DIM * C_DIM;
        const ushortT* wkT_l = wkT + (size_t)l * C_DIM * C_DIM;
        const ushortT* wvT_l = wvT + (size_t)l * C_DIM * C_DIM;
        const ushortT* woT_l = woT + (size_t)l * C_DIM * C_DIM;
        const ushortT* w1T_l = w1T + (size_t)l * C_DIM * 4 * C_DIM;
        const ushortT* w2T_l = w2T + (size_t)l * C_DIM * 4 * C_DIM;

        ln_kernel<<<N_TOK / 4, 256, 0, stream>>>(x_bf, ln1_g + l * C_DIM, ln1_b + l * C_DIM, h_bf);
        gemm_qkv<<<gemmQKV, 256, 0, stream>>>(h_bf, wqT_l, wkT_l, wvT_l, q_bf, k_bf, v_bf, C_DIM, C_DIM);
        attn_kernel<<<64 * H_N, 256, 0, stream>>>(q_bf, k_bf, v_bf, att_bf);
        gemm_k64_res<<<gemmCC, 256, 0, stream>>>(att_bf, woT_l, bo + l * C_DIM, x_bf, x_bf, C_DIM, C_DIM);
        ln_kernel<<<N_TOK / 4, 256, 0, stream>>>(x_bf, ln2_g + l * C_DIM, ln2_b + l * C_DIM, h_bf);
        gemm_bf16<2><<<gemmC4, 256, 0, stream>>>(h_bf, w1T_l, b1 + (size_t)l * 4 * C_DIM, ff1_bf, 4 * C_DIM, C_DIM);
        gemm_k64_res<<<gemmCC, 256, 0, stream>>>(ff1_bf, w2T_l, b2 + l * C_DIM, x_bf, x_bf, C_DIM, 4 * C_DIM);
    }

    // final LN (bf16) + MFMA LM head -> f32 logits
    ln_kernel<<<N_TOK / 4, 256, 0, stream>>>(x_bf, lnf_g, lnf_b, h_bf);
    gemm_bf16<4><<<dim3(N_TOK / 128, 1), 256, 0, stream>>>(h_bf, lmT, lm_b, out, V_SZ, C_DIM);

    rowloss_kernel<<<N_TOK / 4, 256, 0, stream>>>(out, targets, rl);
    reduce_loss_kernel<<<1, 256, 0, stream>>>(rl, out + (size_t)N_TOK * V_SZ);
}